// Round 2
// baseline (828.292 us; speedup 1.0000x reference)
//
#include <hip/hip_runtime.h>
#include <math.h>

// ---------------------------------------------------------------------------
// GPT transformer block, internal bf16 compute / fp32 accumulate.
// B=4, T=2048, D=1024 (8192 rows), 3D=3072, 4D=4096.
// Input/output dtype (fp32 vs bf16) detected at runtime on device (flag in ws):
// bf16 arrays have well-formed exponents at EVEN u16 indices; fp32 arrays have
// mantissa garbage there. All raw-side readers/writers branch uniformly on it.
// ---------------------------------------------------------------------------

typedef unsigned short u16;
typedef __attribute__((ext_vector_type(8))) short bf16x8;   // 8 bf16 = 4 VGPRs
typedef __attribute__((ext_vector_type(4))) float f32x4;

#define DEV __device__ __forceinline__

DEV float bf2f(u16 h) {
    union { unsigned u; float f; } t; t.u = ((unsigned)h) << 16; return t.f;
}
DEV u16 f2bf(float f) {
    union { unsigned u; float f; } t; t.f = f;
    unsigned u = t.u;
    return (u16)((u + 0x7FFFu + ((u >> 16) & 1u)) >> 16);   // round-nearest-even
}
// read element i of a raw buffer that is bf16 (isbf=1) or fp32 (isbf=0)
DEV float loadIn(const void* p, long i, int isbf) {
    return isbf ? bf2f(((const u16*)p)[i]) : ((const float*)p)[i];
}

DEV float waveSum(float v) {
    #pragma unroll
    for (int o = 32; o > 0; o >>= 1) v += __shfl_down(v, o, 64);
    return v;
}
DEV float waveMax(float v) {
    #pragma unroll
    for (int o = 32; o > 0; o >>= 1) v = fmaxf(v, __shfl_down(v, o, 64));
    return v;
}

template <bool IS_MAX>
DEV float blockReduce(float v) {
    __shared__ float tmp[5];
    __syncthreads();
    v = IS_MAX ? waveMax(v) : waveSum(v);
    int lane = threadIdx.x & 63, w = threadIdx.x >> 6;
    if (lane == 0) tmp[w] = v;
    __syncthreads();
    if (threadIdx.x == 0) {
        float r = tmp[0];
        for (int i = 1; i < 4; i++) r = IS_MAX ? fmaxf(r, tmp[i]) : (r + tmp[i]);
        tmp[4] = r;
    }
    __syncthreads();
    return tmp[4];
}

// ---------------- dtype detection (1 block) --------------------------------
__global__ void detect_dtype(const u16* __restrict__ xr, int* __restrict__ flag) {
    const int tid = threadIdx.x;           // 256
    int cnt = 0;
    #pragma unroll
    for (int i = 0; i < 16; i++) {
        unsigned u = xr[2 * (tid + 256 * i)];      // even u16 indices
        unsigned e = (u >> 7) & 0xFF;              // bf16 exponent field
        cnt += (e >= 100 && e <= 140) ? 1 : 0;     // ~always for bf16 N(0,1)
    }
    __shared__ int sh[4];
    #pragma unroll
    for (int o = 32; o > 0; o >>= 1) cnt += __shfl_down(cnt, o, 64);
    if ((tid & 63) == 0) sh[tid >> 6] = cnt;
    __syncthreads();
    if (tid == 0) flag[0] = (sh[0] + sh[1] + sh[2] + sh[3] > 2048) ? 1 : 0;
}

// ---------------- LayerNorm (D=1024, one 256-thread block per row) ---------
// RAW_IN: input dtype follows flag; otherwise input is internal bf16.
template <bool RAW_IN>
__global__ void ln_kernel(const void* __restrict__ x, const void* __restrict__ g,
                          const void* __restrict__ b, u16* __restrict__ out,
                          const int* __restrict__ flagp) {
    const int isbf = *flagp;
    const int inbf = RAW_IN ? isbf : 1;
    const long base = (long)blockIdx.x * 1024;
    const int tid = threadIdx.x;
    float v[4];
    #pragma unroll
    for (int j = 0; j < 4; j++) v[j] = loadIn(x, base + tid + 256 * j, inbf);
    float mu = blockReduce<false>(v[0] + v[1] + v[2] + v[3]) * (1.0f / 1024.0f);
    float d[4], sq = 0.f;
    #pragma unroll
    for (int j = 0; j < 4; j++) { d[j] = v[j] - mu; sq += d[j] * d[j]; }
    float var = blockReduce<false>(sq) * (1.0f / 1024.0f);
    float rstd = rsqrtf(var + 1e-5f);
    #pragma unroll
    for (int j = 0; j < 4; j++) {
        int c = tid + 256 * j;
        out[base + c] = f2bf(d[j] * rstd * loadIn(g, c, isbf) + loadIn(b, c, isbf));
    }
}

// ---------------- 32x32 transpose -> bf16 ----------------------------------
// flagp != nullptr: input dtype follows flag. flagp == nullptr: input is bf16.
__global__ void transpose_to_bf16(const void* __restrict__ in, int ldin, long inBatch,
                                  u16* __restrict__ out, int ldout, long outBatch,
                                  const int* __restrict__ flagp) {
    __shared__ u16 tile[32][33];
    const int isbf = flagp ? *flagp : 1;
    const long ibase = (long)blockIdx.z * inBatch;
    out += (long)blockIdx.z * outBatch;
    const int bc = blockIdx.x * 32, br = blockIdx.y * 32;
    const int tx = threadIdx.x & 31, ty = threadIdx.x >> 5;   // 256 thr
    #pragma unroll
    for (int i = 0; i < 32; i += 8)
        tile[ty + i][tx] = f2bf(loadIn(in, ibase + (long)(br + ty + i) * ldin + bc + tx, isbf));
    __syncthreads();
    #pragma unroll
    for (int i = 0; i < 32; i += 8)
        out[(long)(bc + ty + i) * ldout + br + tx] = tile[tx][ty + i];
}

// ---------------- GEMM: C[M,N] = A[M,K] @ (B^T[N,K])^T (+epilogue) ---------
// A, Bt always internal bf16. MODE:
//  0 qkv : +bias(raw)                   -> bf16
//  1 sc  : *scale                       -> fp32
//  2 pv  : plain                        -> bf16
//  3 proj: +bias(raw) +res(raw)         -> bf16
//  4 fc  : +bias(raw), gelu             -> bf16
//  5 fc2 : +bias(raw) +res(bf16)        -> flag dtype (d_out)
template <int MODE>
__global__ void gemm_bt(const u16* __restrict__ A, int lda, long aBatch,
                        const u16* __restrict__ Bt, int ldb, long bBatch,
                        const void* __restrict__ bias,
                        void* __restrict__ Cv, int ldc, long cBatch,
                        const void* __restrict__ res,
                        float scale, const int* __restrict__ flagp, int K) {
    __shared__ __align__(16) u16 sA[64][40];   // pad 32->40 (80 B pitch, 16B-aligned)
    __shared__ __align__(16) u16 sB[64][40];
    const int bz = blockIdx.z;
    A  += (long)bz * aBatch;
    Bt += (long)bz * bBatch;
    const int m0 = blockIdx.y * 64, n0 = blockIdx.x * 64;
    const int tid = threadIdx.x;
    const int wave = tid >> 6, lane = tid & 63;
    const int quad = lane >> 4, l16 = lane & 15;
    const int wm = (wave >> 1) * 32, wn = (wave & 1) * 32;
    const int srow = tid >> 2, scol = (tid & 3) * 8;

    f32x4 acc[2][2];
    #pragma unroll
    for (int i = 0; i < 2; i++)
        #pragma unroll
        for (int j = 0; j < 2; j++)
            acc[i][j] = f32x4{0.f, 0.f, 0.f, 0.f};

    const u16* aptr = A  + (long)(m0 + srow) * lda + scol;
    const u16* bptr = Bt + (long)(n0 + srow) * ldb + scol;

    for (int k0 = 0; k0 < K; k0 += 32) {
        bf16x8 av = *reinterpret_cast<const bf16x8*>(aptr + k0);
        bf16x8 bv = *reinterpret_cast<const bf16x8*>(bptr + k0);
        __syncthreads();
        *reinterpret_cast<bf16x8*>(&sA[srow][scol]) = av;
        *reinterpret_cast<bf16x8*>(&sB[srow][scol]) = bv;
        __syncthreads();
        bf16x8 af[2], bfr[2];
        af[0]  = *reinterpret_cast<const bf16x8*>(&sA[wm + l16][quad * 8]);
        af[1]  = *reinterpret_cast<const bf16x8*>(&sA[wm + 16 + l16][quad * 8]);
        bfr[0] = *reinterpret_cast<const bf16x8*>(&sB[wn + l16][quad * 8]);
        bfr[1] = *reinterpret_cast<const bf16x8*>(&sB[wn + 16 + l16][quad * 8]);
        #pragma unroll
        for (int i = 0; i < 2; i++)
            #pragma unroll
            for (int j = 0; j < 2; j++)
                acc[i][j] = __builtin_amdgcn_mfma_f32_16x16x32_bf16(
                    af[i], bfr[j], acc[i][j], 0, 0, 0);
    }

    const int isbf = (MODE == 0 || MODE == 3 || MODE == 4 || MODE == 5) ? *flagp : 1;
    #pragma unroll
    for (int i = 0; i < 2; i++) {
        #pragma unroll
        for (int j = 0; j < 2; j++) {
            #pragma unroll
            for (int r = 0; r < 4; r++) {
                const int row = m0 + wm + 16 * i + quad * 4 + r;
                const int col = n0 + wn + 16 * j + l16;
                const long idx = (long)bz * cBatch + (long)row * ldc + col;
                float v = acc[i][j][r];
                if (MODE == 1) {
                    reinterpret_cast<float*>(Cv)[idx] = v * scale;
                } else {
                    if (MODE != 2) v += loadIn(bias, col, isbf);
                    if (MODE == 4) {
                        float xx = v;
                        v = 0.5f * xx * (1.0f + tanhf(0.7978845608028654f *
                                (xx + 0.044715f * xx * xx * xx)));
                    }
                    if (MODE == 3) v += loadIn(res, (long)row * ldc + col, isbf);
                    if (MODE == 5) v += bf2f(((const u16*)res)[(long)row * ldc + col]);
                    if (MODE == 5 && !isbf)
                        reinterpret_cast<float*>(Cv)[idx] = v;
                    else
                        reinterpret_cast<u16*>(Cv)[idx] = f2bf(v);
                }
            }
        }
    }
}

// ---------------- causal softmax: fp32 scores -> bf16 probs ----------------
__global__ void softmax_causal(const float* __restrict__ S, u16* __restrict__ P) {
    const long row = blockIdx.x;
    const int t = (int)(row & 2047);
    const float* sr = S + row * 2048;
    u16* pr = P + row * 2048;
    const int tid = threadIdx.x;
    float v[8];
    float mx = -INFINITY;
    #pragma unroll
    for (int i = 0; i < 8; i++) {
        int s = tid * 8 + i;
        float x = sr[s];
        v[i] = (s <= t) ? x : -INFINITY;
        mx = fmaxf(mx, v[i]);
    }
    mx = blockReduce<true>(mx);
    float sum = 0.f;
    #pragma unroll
    for (int i = 0; i < 8; i++) {
        int s = tid * 8 + i;
        float e = (s <= t) ? __expf(v[i] - mx) : 0.0f;
        v[i] = e;
        sum += e;
    }
    sum = blockReduce<false>(sum);
    float inv = 1.0f / sum;
    #pragma unroll
    for (int i = 0; i < 8; i++)
        pr[tid * 8 + i] = f2bf(v[i] * inv);
}

// ---------------------------------------------------------------------------
extern "C" void kernel_launch(void* const* d_in, const int* in_sizes, int n_in,
                              void* d_out, int out_size, void* d_ws, size_t ws_size,
                              hipStream_t stream) {
    const void* x      = d_in[0];
    const void* w_attn = d_in[1];
    const void* b_attn = d_in[2];
    const void* w_proj = d_in[3];
    const void* b_proj = d_in[4];
    const void* ln1_g  = d_in[5];
    const void* ln1_b  = d_in[6];
    const void* ln2_g  = d_in[7];
    const void* ln2_b  = d_in[8];
    const void* w_fc   = d_in[9];
    const void* b_fc   = d_in[10];
    const void* w_fc2  = d_in[11];
    const void* b_fc2  = d_in[12];

    // workspace layout (176.16 MB + 256 B flag)
    char* ws = (char*)d_ws;
    u16*   hbuf   = (u16*)(ws);                      // 16.78 MB: h -> y -> h2
    u16*   qkv    = (u16*)(ws + 16777216);           // 50.33 MB (later: probs+x1)
    float* S      = (float*)(ws + 67108864);         // 67.11 MB (later: g1 bf16)
    u16*   wattnT = (u16*)(ws + 134217728);          // 25.17 MB of w^T
    u16*   wprojT = wattnT + 3072 * 1024;
    u16*   wfcT   = wprojT + 1024 * 1024;
    u16*   wfc2T  = wfcT + 4096 * 1024;
    u16*   vT     = wfc2T + 1024 * 4096;             // 16.78 MB @ 159,383,552
    int*   flag   = (int*)(ws + 176160768);
    u16*   probs  = qkv;                   // reuses qkv region after scores
    u16*   x1     = qkv + 16777216;        // byte offset 33.5 MB within qkv region

    detect_dtype<<<1, 256, 0, stream>>>((const u16*)x, flag);

    // weight transposes (raw dtype -> bf16)
    transpose_to_bf16<<<dim3(96, 32, 1),  256, 0, stream>>>(w_attn, 3072, 0, wattnT, 1024, 0, flag);
    transpose_to_bf16<<<dim3(32, 32, 1),  256, 0, stream>>>(w_proj, 1024, 0, wprojT, 1024, 0, flag);
    transpose_to_bf16<<<dim3(128, 32, 1), 256, 0, stream>>>(w_fc,   4096, 0, wfcT,   1024, 0, flag);
    transpose_to_bf16<<<dim3(32, 128, 1), 256, 0, stream>>>(w_fc2,  1024, 0, wfc2T,  4096, 0, flag);

    // h = LN1(x)
    ln_kernel<true><<<8192, 256, 0, stream>>>(x, ln1_g, ln1_b, hbuf, flag);

    // qkv = h @ w_attn + b_attn       [8192, 3072]
    gemm_bt<0><<<dim3(48, 128, 1), 256, 0, stream>>>(
        hbuf, 1024, 0, wattnT, 1024, 0, b_attn, qkv, 3072, 0, nullptr, 0.f, flag, 1024);

    // vT[b] = V[b]^T                   [1024, 2048] x4 (internal bf16 input)
    transpose_to_bf16<<<dim3(32, 64, 4), 256, 0, stream>>>(
        qkv + 2048, 3072, (long)2048 * 3072, vT, 2048, (long)1024 * 2048, nullptr);

    // S[b] = 0.125 * q[b] @ k[b]^T    [2048, 2048] fp32 x4
    gemm_bt<1><<<dim3(32, 32, 4), 256, 0, stream>>>(
        qkv, 3072, (long)2048 * 3072, qkv + 1024, 3072, (long)2048 * 3072,
        nullptr, S, 2048, (long)2048 * 2048, nullptr, 0.125f, flag, 1024);

    // probs = causal softmax(S)  (qkv region is dead now; probs ld=2048)
    softmax_causal<<<8192, 256, 0, stream>>>(S, probs);

    // y[b] = P[b] @ V[b]              [2048, 1024] x4  -> hbuf
    gemm_bt<2><<<dim3(16, 32, 4), 256, 0, stream>>>(
        probs, 2048, (long)2048 * 2048, vT, 2048, (long)1024 * 2048,
        nullptr, hbuf, 1024, (long)2048 * 1024, nullptr, 0.f, flag, 2048);

    // x1 = x + y @ w_proj + b_proj    (bf16, in ws)
    gemm_bt<3><<<dim3(16, 128, 1), 256, 0, stream>>>(
        hbuf, 1024, 0, wprojT, 1024, 0, b_proj, x1, 1024, 0, x, 0.f, flag, 1024);

    // h2 = LN2(x1) -> hbuf
    ln_kernel<false><<<8192, 256, 0, stream>>>(x1, ln2_g, ln2_b, hbuf, flag);

    // g1 = gelu(h2 @ w_fc + b_fc)     [8192, 4096] bf16 in S region
    gemm_bt<4><<<dim3(64, 128, 1), 256, 0, stream>>>(
        hbuf, 1024, 0, wfcT, 1024, 0, b_fc, (u16*)S, 4096, 0, nullptr, 0.f, flag, 1024);

    // out = x1 + g1 @ w_fc2 + b_fc2   (written in detected dtype)
    gemm_bt<5><<<dim3(16, 128, 1), 256, 0, stream>>>(
        (u16*)S, 4096, 0, wfc2T, 4096, 0, b_fc2, d_out, 1024, 0, x1, 0.f, flag, 4096);
}

// Round 3
// 725.714 us; speedup vs baseline: 1.1413x; 1.1413x over previous
//
#include <hip/hip_runtime.h>
#include <math.h>

// ---------------------------------------------------------------------------
// GPT transformer block, internal bf16 compute / fp32 accumulate.
// B=4, T=2048, D=1024 (8192 rows), 3D=3072, 4D=4096.
// Round 3: m97-class GEMM — 128x128 block tile, 4 waves x (4x4) 16x16x32
// MFMA frags, BK=32, global_load_lds width=16 staging (unpadded LDS tiles),
// causal block-skip in scores gemm + K-clamp in P@V gemm.
// ---------------------------------------------------------------------------

typedef unsigned short u16;
typedef __attribute__((ext_vector_type(8))) short bf16x8;   // 8 bf16 = 4 VGPRs
typedef __attribute__((ext_vector_type(4))) float f32x4;

#define DEV __device__ __forceinline__

#define GLOAD_LDS16(gp, lp)                                                     \
    __builtin_amdgcn_global_load_lds(                                           \
        (const __attribute__((address_space(1))) void*)(gp),                    \
        (__attribute__((address_space(3))) void*)(lp), 16, 0, 0)

DEV float bf2f(u16 h) {
    union { unsigned u; float f; } t; t.u = ((unsigned)h) << 16; return t.f;
}
DEV u16 f2bf(float f) {
    union { unsigned u; float f; } t; t.f = f;
    unsigned u = t.u;
    return (u16)((u + 0x7FFFu + ((u >> 16) & 1u)) >> 16);   // round-nearest-even
}
DEV float loadIn(const void* p, long i, int isbf) {
    return isbf ? bf2f(((const u16*)p)[i]) : ((const float*)p)[i];
}

DEV float waveSum(float v) {
    #pragma unroll
    for (int o = 32; o > 0; o >>= 1) v += __shfl_down(v, o, 64);
    return v;
}
DEV float waveMax(float v) {
    #pragma unroll
    for (int o = 32; o > 0; o >>= 1) v = fmaxf(v, __shfl_down(v, o, 64));
    return v;
}

template <bool IS_MAX>
DEV float blockReduce(float v) {
    __shared__ float tmp[5];
    __syncthreads();
    v = IS_MAX ? waveMax(v) : waveSum(v);
    int lane = threadIdx.x & 63, w = threadIdx.x >> 6;
    if (lane == 0) tmp[w] = v;
    __syncthreads();
    if (threadIdx.x == 0) {
        float r = tmp[0];
        for (int i = 1; i < 4; i++) r = IS_MAX ? fmaxf(r, tmp[i]) : (r + tmp[i]);
        tmp[4] = r;
    }
    __syncthreads();
    return tmp[4];
}

// ---------------- dtype detection (1 block) --------------------------------
__global__ void detect_dtype(const u16* __restrict__ xr, int* __restrict__ flag) {
    const int tid = threadIdx.x;           // 256
    int cnt = 0;
    #pragma unroll
    for (int i = 0; i < 16; i++) {
        unsigned u = xr[2 * (tid + 256 * i)];      // even u16 indices
        unsigned e = (u >> 7) & 0xFF;              // bf16 exponent field
        cnt += (e >= 100 && e <= 140) ? 1 : 0;     // ~always for bf16 N(0,1)
    }
    __shared__ int sh[4];
    #pragma unroll
    for (int o = 32; o > 0; o >>= 1) cnt += __shfl_down(cnt, o, 64);
    if ((tid & 63) == 0) sh[tid >> 6] = cnt;
    __syncthreads();
    if (tid == 0) flag[0] = (sh[0] + sh[1] + sh[2] + sh[3] > 2048) ? 1 : 0;
}

// ---------------- LayerNorm (D=1024, one 256-thread block per row) ---------
template <bool RAW_IN>
__global__ void ln_kernel(const void* __restrict__ x, const void* __restrict__ g,
                          const void* __restrict__ b, u16* __restrict__ out,
                          const int* __restrict__ flagp) {
    const int isbf = *flagp;
    const int inbf = RAW_IN ? isbf : 1;
    const long base = (long)blockIdx.x * 1024;
    const int tid = threadIdx.x;
    float v[4];
    #pragma unroll
    for (int j = 0; j < 4; j++) v[j] = loadIn(x, base + tid + 256 * j, inbf);
    float mu = blockReduce<false>(v[0] + v[1] + v[2] + v[3]) * (1.0f / 1024.0f);
    float d[4], sq = 0.f;
    #pragma unroll
    for (int j = 0; j < 4; j++) { d[j] = v[j] - mu; sq += d[j] * d[j]; }
    float var = blockReduce<false>(sq) * (1.0f / 1024.0f);
    float rstd = rsqrtf(var + 1e-5f);
    #pragma unroll
    for (int j = 0; j < 4; j++) {
        int c = tid + 256 * j;
        out[base + c] = f2bf(d[j] * rstd * loadIn(g, c, isbf) + loadIn(b, c, isbf));
    }
}

// ---------------- 32x32 transpose -> bf16 ----------------------------------
__global__ void transpose_to_bf16(const void* __restrict__ in, int ldin, long inBatch,
                                  u16* __restrict__ out, int ldout, long outBatch,
                                  const int* __restrict__ flagp) {
    __shared__ u16 tile[32][33];
    const int isbf = flagp ? *flagp : 1;
    const long ibase = (long)blockIdx.z * inBatch;
    out += (long)blockIdx.z * outBatch;
    const int bc = blockIdx.x * 32, br = blockIdx.y * 32;
    const int tx = threadIdx.x & 31, ty = threadIdx.x >> 5;   // 256 thr
    #pragma unroll
    for (int i = 0; i < 32; i += 8)
        tile[ty + i][tx] = f2bf(loadIn(in, ibase + (long)(br + ty + i) * ldin + bc + tx, isbf));
    __syncthreads();
    #pragma unroll
    for (int i = 0; i < 32; i += 8)
        out[(long)(bc + ty + i) * ldout + br + tx] = tile[tx][ty + i];
}

// ---------------- GEMM: C[M,N] = A[M,K] @ (B^T[N,K])^T (+epilogue) ---------
// A, Bt internal bf16. 128x128 tile, BK=32, global_load_lds staging.
// MODE: 0 qkv +bias(raw)->bf16        1 sc *scale->fp32
//       2 pv  plain->bf16             3 proj +bias(raw)+res(raw)->bf16
//       4 fc  +bias(raw),gelu->bf16   5 fc2 +bias(raw)+res(bf16)->flag dtype
// CAUSAL: 0 none, 1 skip blocks with n0>m0 (scores), 2 clamp K to m0+128 (pv)
template <int MODE, int CAUSAL>
__global__ __launch_bounds__(256) void gemm128(
        const u16* __restrict__ A, int lda, long aBatch,
        const u16* __restrict__ Bt, int ldb, long bBatch,
        const void* __restrict__ bias,
        void* __restrict__ Cv, int ldc, long cBatch,
        const void* __restrict__ res,
        float scale, const int* __restrict__ flagp, int K) {
    const int m0 = blockIdx.y * 128, n0 = blockIdx.x * 128;
    if (CAUSAL == 1 && n0 > m0) return;            // fully-masked score block
    __shared__ __align__(16) u16 sA[128 * 32];     // unpadded: global_load_lds
    __shared__ __align__(16) u16 sB[128 * 32];     // dest is base + lane*16
    const int bz = blockIdx.z;
    A  += (long)bz * aBatch + (long)m0 * lda;
    Bt += (long)bz * bBatch + (long)n0 * ldb;
    const int tid = threadIdx.x;
    const int wave = tid >> 6, lane = tid & 63;
    const int quad = lane >> 4, l16 = lane & 15;
    const int wr = (wave >> 1) * 64, wc = (wave & 1) * 64;

    // staging map: chunk = 16B unit; lane l of wave w owns chunks
    // {64w+l, 64w+l+256}; LDS offset = chunk*16B; global row = chunk>>2.
    const int chunk = wave * 64 + lane;
    const int crow = chunk >> 2;
    const int ccol = (chunk & 3) * 8;
    const u16* ag = A  + (long)crow * lda + ccol;
    const u16* bg = Bt + (long)crow * ldb + ccol;
    u16* sAd = sA + chunk * 8;                     // elem offset = chunk*8
    u16* sBd = sB + chunk * 8;
    const long aStep = (long)64 * lda, bStep = (long)64 * ldb;

    f32x4 acc[4][4];
    #pragma unroll
    for (int i = 0; i < 4; i++)
        #pragma unroll
        for (int j = 0; j < 4; j++)
            acc[i][j] = f32x4{0.f, 0.f, 0.f, 0.f};

    int Keff = K;
    if (CAUSAL == 2) Keff = min(K, m0 + 128);      // probs are 0 past diagonal

    for (int k0 = 0; k0 < Keff; k0 += 32) {
        __syncthreads();                           // prior iter's LDS reads done
        GLOAD_LDS16(ag + k0,         sAd);
        GLOAD_LDS16(ag + k0 + aStep, sAd + 2048);
        GLOAD_LDS16(bg + k0,         sBd);
        GLOAD_LDS16(bg + k0 + bStep, sBd + 2048);
        __syncthreads();                           // staging landed (vmcnt drain)
        bf16x8 af[4], bfv[4];
        #pragma unroll
        for (int i = 0; i < 4; i++) {
            af[i]  = *reinterpret_cast<const bf16x8*>(&sA[(wr + 16 * i + l16) * 32 + quad * 8]);
            bfv[i] = *reinterpret_cast<const bf16x8*>(&sB[(wc + 16 * i + l16) * 32 + quad * 8]);
        }
        #pragma unroll
        for (int i = 0; i < 4; i++)
            #pragma unroll
            for (int j = 0; j < 4; j++)
                acc[i][j] = __builtin_amdgcn_mfma_f32_16x16x32_bf16(
                    af[i], bfv[j], acc[i][j], 0, 0, 0);
    }

    const int isbf = (MODE == 0 || MODE == 3 || MODE == 4 || MODE == 5) ? *flagp : 1;
    #pragma unroll
    for (int i = 0; i < 4; i++) {
        #pragma unroll
        for (int j = 0; j < 4; j++) {
            #pragma unroll
            for (int r = 0; r < 4; r++) {
                const int row = m0 + wr + 16 * i + quad * 4 + r;
                const int col = n0 + wc + 16 * j + l16;
                const long idx = (long)bz * cBatch + (long)row * ldc + col;
                float v = acc[i][j][r];
                if (MODE == 1) {
                    reinterpret_cast<float*>(Cv)[idx] = v * scale;
                } else {
                    if (MODE != 2) v += loadIn(bias, col, isbf);
                    if (MODE == 4) {
                        float xx = v;
                        v = 0.5f * xx * (1.0f + tanhf(0.7978845608028654f *
                                (xx + 0.044715f * xx * xx * xx)));
                    }
                    if (MODE == 3) v += loadIn(res, (long)row * ldc + col, isbf);
                    if (MODE == 5) v += bf2f(((const u16*)res)[(long)row * ldc + col]);
                    if (MODE == 5 && !isbf)
                        reinterpret_cast<float*>(Cv)[idx] = v;
                    else
                        reinterpret_cast<u16*>(Cv)[idx] = f2bf(v);
                }
            }
        }
    }
}

// ---------------- causal softmax: fp32 scores -> bf16 probs ----------------
__global__ void softmax_causal(const float* __restrict__ S, u16* __restrict__ P) {
    const long row = blockIdx.x;
    const int t = (int)(row & 2047);
    const float* sr = S + row * 2048;
    u16* pr = P + row * 2048;
    const int tid = threadIdx.x;
    float v[8];
    float mx = -INFINITY;
    #pragma unroll
    for (int i = 0; i < 8; i++) {
        int s = tid * 8 + i;
        float x = sr[s];
        v[i] = (s <= t) ? x : -INFINITY;
        mx = fmaxf(mx, v[i]);
    }
    mx = blockReduce<true>(mx);
    float sum = 0.f;
    #pragma unroll
    for (int i = 0; i < 8; i++) {
        int s = tid * 8 + i;
        float e = (s <= t) ? __expf(v[i] - mx) : 0.0f;
        v[i] = e;
        sum += e;
    }
    sum = blockReduce<false>(sum);
    float inv = 1.0f / sum;
    #pragma unroll
    for (int i = 0; i < 8; i++)
        pr[tid * 8 + i] = f2bf(v[i] * inv);
}

// ---------------------------------------------------------------------------
extern "C" void kernel_launch(void* const* d_in, const int* in_sizes, int n_in,
                              void* d_out, int out_size, void* d_ws, size_t ws_size,
                              hipStream_t stream) {
    const void* x      = d_in[0];
    const void* w_attn = d_in[1];
    const void* b_attn = d_in[2];
    const void* w_proj = d_in[3];
    const void* b_proj = d_in[4];
    const void* ln1_g  = d_in[5];
    const void* ln1_b  = d_in[6];
    const void* ln2_g  = d_in[7];
    const void* ln2_b  = d_in[8];
    const void* w_fc   = d_in[9];
    const void* b_fc   = d_in[10];
    const void* w_fc2  = d_in[11];
    const void* b_fc2  = d_in[12];

    // workspace layout (176.16 MB + flag)
    char* ws = (char*)d_ws;
    u16*   hbuf   = (u16*)(ws);                      // 16.78 MB: h -> y -> h2
    u16*   qkv    = (u16*)(ws + 16777216);           // 50.33 MB (later: probs+x1)
    float* S      = (float*)(ws + 67108864);         // 67.11 MB (later: g1 bf16)
    u16*   wattnT = (u16*)(ws + 134217728);          // 25.17 MB of w^T
    u16*   wprojT = wattnT + 3072 * 1024;
    u16*   wfcT   = wprojT + 1024 * 1024;
    u16*   wfc2T  = wfcT + 4096 * 1024;
    u16*   vT     = wfc2T + 1024 * 4096;             // 16.78 MB
    int*   flag   = (int*)(ws + 176160768);
    u16*   probs  = qkv;                   // reuses qkv region after scores
    u16*   x1     = qkv + 16777216;

    detect_dtype<<<1, 256, 0, stream>>>((const u16*)x, flag);

    // weight transposes (raw dtype -> bf16)
    transpose_to_bf16<<<dim3(96, 32, 1),  256, 0, stream>>>(w_attn, 3072, 0, wattnT, 1024, 0, flag);
    transpose_to_bf16<<<dim3(32, 32, 1),  256, 0, stream>>>(w_proj, 1024, 0, wprojT, 1024, 0, flag);
    transpose_to_bf16<<<dim3(128, 32, 1), 256, 0, stream>>>(w_fc,   4096, 0, wfcT,   1024, 0, flag);
    transpose_to_bf16<<<dim3(32, 128, 1), 256, 0, stream>>>(w_fc2,  1024, 0, wfc2T,  4096, 0, flag);

    // h = LN1(x)
    ln_kernel<true><<<8192, 256, 0, stream>>>(x, ln1_g, ln1_b, hbuf, flag);

    // qkv = h @ w_attn + b_attn       [8192, 3072]
    gemm128<0, 0><<<dim3(24, 64, 1), 256, 0, stream>>>(
        hbuf, 1024, 0, wattnT, 1024, 0, b_attn, qkv, 3072, 0, nullptr, 0.f, flag, 1024);

    // vT[b] = V[b]^T                   [1024, 2048] x4
    transpose_to_bf16<<<dim3(32, 64, 4), 256, 0, stream>>>(
        qkv + 2048, 3072, (long)2048 * 3072, vT, 2048, (long)1024 * 2048, nullptr);

    // S[b] = 0.125 * q[b] @ k[b]^T    [2048, 2048] fp32 x4, upper blocks skipped
    gemm128<1, 1><<<dim3(16, 16, 4), 256, 0, stream>>>(
        qkv, 3072, (long)2048 * 3072, qkv + 1024, 3072, (long)2048 * 3072,
        nullptr, S, 2048, (long)2048 * 2048, nullptr, 0.125f, flag, 1024);

    // probs = causal softmax(S)
    softmax_causal<<<8192, 256, 0, stream>>>(S, probs);

    // y[b] = P[b] @ V[b]              [2048, 1024] x4, K clamped to diagonal
    gemm128<2, 2><<<dim3(8, 16, 4), 256, 0, stream>>>(
        probs, 2048, (long)2048 * 2048, vT, 2048, (long)1024 * 2048,
        nullptr, hbuf, 1024, (long)2048 * 1024, nullptr, 0.f, flag, 2048);

    // x1 = x + y @ w_proj + b_proj    (bf16, in ws)
    gemm128<3, 0><<<dim3(8, 64, 1), 256, 0, stream>>>(
        hbuf, 1024, 0, wprojT, 1024, 0, b_proj, x1, 1024, 0, x, 0.f, flag, 1024);

    // h2 = LN2(x1) -> hbuf
    ln_kernel<false><<<8192, 256, 0, stream>>>(x1, ln2_g, ln2_b, hbuf, flag);

    // g1 = gelu(h2 @ w_fc + b_fc)     [8192, 4096] bf16 in S region
    gemm128<4, 0><<<dim3(32, 64, 1), 256, 0, stream>>>(
        hbuf, 1024, 0, wfcT, 1024, 0, b_fc, (u16*)S, 4096, 0, nullptr, 0.f, flag, 1024);

    // out = x1 + g1 @ w_fc2 + b_fc2   (written in detected dtype)
    gemm128<5, 0><<<dim3(8, 64, 1), 256, 0, stream>>>(
        (u16*)S, 4096, 0, wfc2T, 4096, 0, b_fc2, d_out, 1024, 0, x1, 0.f, flag, 4096);
}

// Round 4
// 691.096 us; speedup vs baseline: 1.1985x; 1.0501x over previous
//
#include <hip/hip_runtime.h>
#include <math.h>

// ---------------------------------------------------------------------------
// GPT transformer block, internal bf16 compute / fp32 accumulate.
// B=4, T=2048, D=1024 (8192 rows), 3D=3072, 4D=4096.
// Round 4: gemm128 with BK=64 (half the barrier drains), XOR-swizzled LDS
// (kills 8/16-way ds_read_b128 bank conflicts; staging stays contiguous for
// global_load_lds), bf16 scores (halves softmax traffic).
// ---------------------------------------------------------------------------

typedef unsigned short u16;
typedef __attribute__((ext_vector_type(8))) short bf16x8;   // 8 bf16 = 4 VGPRs
typedef __attribute__((ext_vector_type(4))) float f32x4;

#define DEV __device__ __forceinline__

#define GLOAD_LDS16(gp, lp)                                                     \
    __builtin_amdgcn_global_load_lds(                                           \
        (const __attribute__((address_space(1))) void*)(gp),                    \
        (__attribute__((address_space(3))) void*)(lp), 16, 0, 0)

DEV float bf2f(u16 h) {
    union { unsigned u; float f; } t; t.u = ((unsigned)h) << 16; return t.f;
}
DEV u16 f2bf(float f) {
    union { unsigned u; float f; } t; t.f = f;
    unsigned u = t.u;
    return (u16)((u + 0x7FFFu + ((u >> 16) & 1u)) >> 16);   // round-nearest-even
}
DEV float loadIn(const void* p, long i, int isbf) {
    return isbf ? bf2f(((const u16*)p)[i]) : ((const float*)p)[i];
}

DEV float waveSum(float v) {
    #pragma unroll
    for (int o = 32; o > 0; o >>= 1) v += __shfl_down(v, o, 64);
    return v;
}
DEV float waveMax(float v) {
    #pragma unroll
    for (int o = 32; o > 0; o >>= 1) v = fmaxf(v, __shfl_down(v, o, 64));
    return v;
}

template <bool IS_MAX>
DEV float blockReduce(float v) {
    __shared__ float tmp[5];
    __syncthreads();
    v = IS_MAX ? waveMax(v) : waveSum(v);
    int lane = threadIdx.x & 63, w = threadIdx.x >> 6;
    if (lane == 0) tmp[w] = v;
    __syncthreads();
    if (threadIdx.x == 0) {
        float r = tmp[0];
        for (int i = 1; i < 4; i++) r = IS_MAX ? fmaxf(r, tmp[i]) : (r + tmp[i]);
        tmp[4] = r;
    }
    __syncthreads();
    return tmp[4];
}

// ---------------- dtype detection (1 block) --------------------------------
__global__ void detect_dtype(const u16* __restrict__ xr, int* __restrict__ flag) {
    const int tid = threadIdx.x;           // 256
    int cnt = 0;
    #pragma unroll
    for (int i = 0; i < 16; i++) {
        unsigned u = xr[2 * (tid + 256 * i)];      // even u16 indices
        unsigned e = (u >> 7) & 0xFF;              // bf16 exponent field
        cnt += (e >= 100 && e <= 140) ? 1 : 0;     // ~always for bf16 N(0,1)
    }
    __shared__ int sh[4];
    #pragma unroll
    for (int o = 32; o > 0; o >>= 1) cnt += __shfl_down(cnt, o, 64);
    if ((tid & 63) == 0) sh[tid >> 6] = cnt;
    __syncthreads();
    if (tid == 0) flag[0] = (sh[0] + sh[1] + sh[2] + sh[3] > 2048) ? 1 : 0;
}

// ---------------- LayerNorm (D=1024, one 256-thread block per row) ---------
template <bool RAW_IN>
__global__ void ln_kernel(const void* __restrict__ x, const void* __restrict__ g,
                          const void* __restrict__ b, u16* __restrict__ out,
                          const int* __restrict__ flagp) {
    const int isbf = *flagp;
    const int inbf = RAW_IN ? isbf : 1;
    const long base = (long)blockIdx.x * 1024;
    const int tid = threadIdx.x;
    float v[4];
    #pragma unroll
    for (int j = 0; j < 4; j++) v[j] = loadIn(x, base + tid + 256 * j, inbf);
    float mu = blockReduce<false>(v[0] + v[1] + v[2] + v[3]) * (1.0f / 1024.0f);
    float d[4], sq = 0.f;
    #pragma unroll
    for (int j = 0; j < 4; j++) { d[j] = v[j] - mu; sq += d[j] * d[j]; }
    float var = blockReduce<false>(sq) * (1.0f / 1024.0f);
    float rstd = rsqrtf(var + 1e-5f);
    #pragma unroll
    for (int j = 0; j < 4; j++) {
        int c = tid + 256 * j;
        out[base + c] = f2bf(d[j] * rstd * loadIn(g, c, isbf) + loadIn(b, c, isbf));
    }
}

// ---------------- 32x32 transpose -> bf16 ----------------------------------
__global__ void transpose_to_bf16(const void* __restrict__ in, int ldin, long inBatch,
                                  u16* __restrict__ out, int ldout, long outBatch,
                                  const int* __restrict__ flagp) {
    __shared__ u16 tile[32][33];
    const int isbf = flagp ? *flagp : 1;
    const long ibase = (long)blockIdx.z * inBatch;
    out += (long)blockIdx.z * outBatch;
    const int bc = blockIdx.x * 32, br = blockIdx.y * 32;
    const int tx = threadIdx.x & 31, ty = threadIdx.x >> 5;   // 256 thr
    #pragma unroll
    for (int i = 0; i < 32; i += 8)
        tile[ty + i][tx] = f2bf(loadIn(in, ibase + (long)(br + ty + i) * ldin + bc + tx, isbf));
    __syncthreads();
    #pragma unroll
    for (int i = 0; i < 32; i += 8)
        out[(long)(bc + ty + i) * ldout + br + tx] = tile[tx][ty + i];
}

// ---------------- GEMM: C[M,N] = A[M,K] @ (B^T[N,K])^T (+epilogue) ---------
// A, Bt internal bf16. 128x128 tile, BK=64, global_load_lds staging with
// XOR-swizzled LDS layout: global 16B-chunk (row r, q) lives at LDS chunk
// r*8 + (q ^ (r&7)).  Staging dest stays contiguous-by-lane (legal for
// global_load_lds); fragment ds_read_b128 banks become 2-way (free).
// MODE: 0 qkv +bias(raw)->bf16        1 sc *scale->bf16
//       2 pv  plain->bf16             3 proj +bias(raw)+res(raw)->bf16
//       4 fc  +bias(raw),gelu->bf16   5 fc2 +bias(raw)+res(bf16)->flag dtype
// CAUSAL: 0 none, 1 skip blocks with n0>m0 (scores), 2 clamp K to m0+128 (pv)
template <int MODE, int CAUSAL>
__global__ __launch_bounds__(256) void gemm128(
        const u16* __restrict__ A, int lda, long aBatch,
        const u16* __restrict__ Bt, int ldb, long bBatch,
        const void* __restrict__ bias,
        void* __restrict__ Cv, int ldc, long cBatch,
        const void* __restrict__ res,
        float scale, const int* __restrict__ flagp, int K) {
    const int m0 = blockIdx.y * 128, n0 = blockIdx.x * 128;
    if (CAUSAL == 1 && n0 > m0) return;            // fully-masked score block
    __shared__ __align__(16) u16 sA[128 * 64];     // 16 KB each, swizzled
    __shared__ __align__(16) u16 sB[128 * 64];
    const int bz = blockIdx.z;
    A  += (long)bz * aBatch + (long)m0 * lda;
    Bt += (long)bz * bBatch + (long)n0 * ldb;
    const int tid = threadIdx.x;
    const int wave = tid >> 6, lane = tid & 63;
    const int quad = lane >> 4, l16 = lane & 15;
    const int wr = (wave >> 1) * 64, wc = (wave & 1) * 64;

    // staging: tile = 1024 16B-chunks; thread owns chunks c0 + 256k, k=0..3.
    // c = r*8 + (q ^ (r&7)); since 256 | 32-row stride, r0/q0 are k-invariant.
    const int c0 = wave * 64 + lane;
    const int r0 = c0 >> 3;                        // rows 0..31 (+32k later)
    const int q0 = (c0 & 7) ^ (r0 & 7);            // swizzled source col-chunk
    const u16* ag = A  + (long)r0 * lda + q0 * 8;
    const u16* bg = Bt + (long)r0 * ldb + q0 * 8;
    u16* sAd = sA + c0 * 8;
    u16* sBd = sB + c0 * 8;

    f32x4 acc[4][4];
    #pragma unroll
    for (int i = 0; i < 4; i++)
        #pragma unroll
        for (int j = 0; j < 4; j++)
            acc[i][j] = f32x4{0.f, 0.f, 0.f, 0.f};

    int Keff = K;
    if (CAUSAL == 2) Keff = min(K, m0 + 128);      // probs are 0 past diagonal

    for (int k0 = 0; k0 < Keff; k0 += 64) {
        __syncthreads();                           // prior iter's LDS reads done
        #pragma unroll
        for (int k = 0; k < 4; k++) {
            GLOAD_LDS16(ag + k0 + (long)(32 * k) * lda, sAd + 2048 * k);
            GLOAD_LDS16(bg + k0 + (long)(32 * k) * ldb, sBd + 2048 * k);
        }
        __syncthreads();                           // staging landed
        #pragma unroll
        for (int s = 0; s < 2; s++) {
            bf16x8 af[4], bfv[4];
            #pragma unroll
            for (int i = 0; i < 4; i++) {
                const int ra = wr + 16 * i + l16;      // ra&7 == l16&7
                const int qa = (4 * s + quad) ^ (l16 & 7);
                af[i]  = *reinterpret_cast<const bf16x8*>(&sA[ra * 64 + qa * 8]);
                const int rb = wc + 16 * i + l16;
                bfv[i] = *reinterpret_cast<const bf16x8*>(&sB[rb * 64 + qa * 8]);
            }
            #pragma unroll
            for (int i = 0; i < 4; i++)
                #pragma unroll
                for (int j = 0; j < 4; j++)
                    acc[i][j] = __builtin_amdgcn_mfma_f32_16x16x32_bf16(
                        af[i], bfv[j], acc[i][j], 0, 0, 0);
        }
    }

    const int isbf = (MODE == 0 || MODE == 3 || MODE == 4 || MODE == 5) ? *flagp : 1;
    #pragma unroll
    for (int i = 0; i < 4; i++) {
        #pragma unroll
        for (int j = 0; j < 4; j++) {
            #pragma unroll
            for (int r = 0; r < 4; r++) {
                const int row = m0 + wr + 16 * i + quad * 4 + r;
                const int col = n0 + wc + 16 * j + l16;
                const long idx = (long)bz * cBatch + (long)row * ldc + col;
                float v = acc[i][j][r];
                if (MODE == 1) {
                    reinterpret_cast<u16*>(Cv)[idx] = f2bf(v * scale);
                } else {
                    if (MODE != 2) v += loadIn(bias, col, isbf);
                    if (MODE == 4) {
                        float xx = v;
                        v = 0.5f * xx * (1.0f + tanhf(0.7978845608028654f *
                                (xx + 0.044715f * xx * xx * xx)));
                    }
                    if (MODE == 3) v += loadIn(res, (long)row * ldc + col, isbf);
                    if (MODE == 5) v += bf2f(((const u16*)res)[(long)row * ldc + col]);
                    if (MODE == 5 && !isbf)
                        reinterpret_cast<float*>(Cv)[idx] = v;
                    else
                        reinterpret_cast<u16*>(Cv)[idx] = f2bf(v);
                }
            }
        }
    }
}

// ---------------- causal softmax: bf16 scores -> bf16 probs ----------------
__global__ void softmax_causal(const u16* __restrict__ S, u16* __restrict__ P) {
    const long row = blockIdx.x;
    const int t = (int)(row & 2047);
    const u16* sr = S + row * 2048;
    u16* pr = P + row * 2048;
    const int tid = threadIdx.x;
    float v[8];
    float mx = -INFINITY;
    #pragma unroll
    for (int i = 0; i < 8; i++) {
        int s = tid * 8 + i;
        float x = bf2f(sr[s]);
        v[i] = (s <= t) ? x : -INFINITY;
        mx = fmaxf(mx, v[i]);
    }
    mx = blockReduce<true>(mx);
    float sum = 0.f;
    #pragma unroll
    for (int i = 0; i < 8; i++) {
        int s = tid * 8 + i;
        float e = (s <= t) ? __expf(v[i] - mx) : 0.0f;
        v[i] = e;
        sum += e;
    }
    sum = blockReduce<false>(sum);
    float inv = 1.0f / sum;
    #pragma unroll
    for (int i = 0; i < 8; i++)
        pr[tid * 8 + i] = f2bf(v[i] * inv);
}

// ---------------------------------------------------------------------------
extern "C" void kernel_launch(void* const* d_in, const int* in_sizes, int n_in,
                              void* d_out, int out_size, void* d_ws, size_t ws_size,
                              hipStream_t stream) {
    const void* x      = d_in[0];
    const void* w_attn = d_in[1];
    const void* b_attn = d_in[2];
    const void* w_proj = d_in[3];
    const void* b_proj = d_in[4];
    const void* ln1_g  = d_in[5];
    const void* ln1_b  = d_in[6];
    const void* ln2_g  = d_in[7];
    const void* ln2_b  = d_in[8];
    const void* w_fc   = d_in[9];
    const void* b_fc   = d_in[10];
    const void* w_fc2  = d_in[11];
    const void* b_fc2  = d_in[12];

    // workspace layout (176.16 MB + flag)
    char* ws = (char*)d_ws;
    u16*   hbuf   = (u16*)(ws);                      // 16.78 MB: h -> y -> h2
    u16*   qkv    = (u16*)(ws + 16777216);           // 50.33 MB (later: probs+x1)
    u16*   S      = (u16*)(ws + 67108864);           // 33.5 MB bf16 scores (later: g1)
    u16*   wattnT = (u16*)(ws + 134217728);          // 25.17 MB of w^T
    u16*   wprojT = wattnT + 3072 * 1024;
    u16*   wfcT   = wprojT + 1024 * 1024;
    u16*   wfc2T  = wfcT + 4096 * 1024;
    u16*   vT     = wfc2T + 1024 * 4096;             // 16.78 MB
    int*   flag   = (int*)(ws + 176160768);
    u16*   probs  = qkv;                   // reuses qkv region after scores
    u16*   x1     = qkv + 16777216;

    detect_dtype<<<1, 256, 0, stream>>>((const u16*)x, flag);

    // weight transposes (raw dtype -> bf16)
    transpose_to_bf16<<<dim3(96, 32, 1),  256, 0, stream>>>(w_attn, 3072, 0, wattnT, 1024, 0, flag);
    transpose_to_bf16<<<dim3(32, 32, 1),  256, 0, stream>>>(w_proj, 1024, 0, wprojT, 1024, 0, flag);
    transpose_to_bf16<<<dim3(128, 32, 1), 256, 0, stream>>>(w_fc,   4096, 0, wfcT,   1024, 0, flag);
    transpose_to_bf16<<<dim3(32, 128, 1), 256, 0, stream>>>(w_fc2,  1024, 0, wfc2T,  4096, 0, flag);

    // h = LN1(x)
    ln_kernel<true><<<8192, 256, 0, stream>>>(x, ln1_g, ln1_b, hbuf, flag);

    // qkv = h @ w_attn + b_attn       [8192, 3072]
    gemm128<0, 0><<<dim3(24, 64, 1), 256, 0, stream>>>(
        hbuf, 1024, 0, wattnT, 1024, 0, b_attn, qkv, 3072, 0, nullptr, 0.f, flag, 1024);

    // vT[b] = V[b]^T                   [1024, 2048] x4
    transpose_to_bf16<<<dim3(32, 64, 4), 256, 0, stream>>>(
        qkv + 2048, 3072, (long)2048 * 3072, vT, 2048, (long)1024 * 2048, nullptr);

    // S[b] = 0.125 * q[b] @ k[b]^T    [2048, 2048] bf16 x4, upper blocks skipped
    gemm128<1, 1><<<dim3(16, 16, 4), 256, 0, stream>>>(
        qkv, 3072, (long)2048 * 3072, qkv + 1024, 3072, (long)2048 * 3072,
        nullptr, S, 2048, (long)2048 * 2048, nullptr, 0.125f, flag, 1024);

    // probs = causal softmax(S)
    softmax_causal<<<8192, 256, 0, stream>>>(S, probs);

    // y[b] = P[b] @ V[b]              [2048, 1024] x4, K clamped to diagonal
    gemm128<2, 2><<<dim3(8, 16, 4), 256, 0, stream>>>(
        probs, 2048, (long)2048 * 2048, vT, 2048, (long)1024 * 2048,
        nullptr, hbuf, 1024, (long)2048 * 1024, nullptr, 0.f, flag, 2048);

    // x1 = x + y @ w_proj + b_proj    (bf16, in ws)
    gemm128<3, 0><<<dim3(8, 64, 1), 256, 0, stream>>>(
        hbuf, 1024, 0, wprojT, 1024, 0, b_proj, x1, 1024, 0, x, 0.f, flag, 1024);

    // h2 = LN2(x1) -> hbuf
    ln_kernel<false><<<8192, 256, 0, stream>>>(x1, ln2_g, ln2_b, hbuf, flag);

    // g1 = gelu(h2 @ w_fc + b_fc)     [8192, 4096] bf16 in S region
    gemm128<4, 0><<<dim3(32, 64, 1), 256, 0, stream>>>(
        hbuf, 1024, 0, wfcT, 1024, 0, b_fc, S, 4096, 0, nullptr, 0.f, flag, 1024);

    // out = x1 + g1 @ w_fc2 + b_fc2   (written in detected dtype)
    gemm128<5, 0><<<dim3(8, 64, 1), 256, 0, stream>>>(
        S, 4096, 0, wfc2T, 4096, 0, b_fc2, d_out, 1024, 0, x1, 0.f, flag, 4096);
}